// Round 9
// baseline (375.542 us; speedup 1.0000x reference)
//
#include <hip/hip_runtime.h>
#include <hip/hip_cooperative_groups.h>

namespace cg = cooperative_groups;

#define N_NODES 10000
#define D 128
#define N_EDGES 640000
#define SHARDS 8
#define CSTRIDE 10016     // per-shard counter stride (ints); shards on distinct lines
#define BCAP 32           // slots per (node,shard) bucket; 32 * 2B = one 64B line
#define GEMM_BLOCKS 313   // ceil(10000/32)
#define NBLK 1024         // cooperative grid: 4 blocks/CU on 256 CUs
#define FILL_BLOCKS 2500  // fallback path

// bf16 round-to-nearest-even
__device__ __forceinline__ unsigned short f2bf(float f) {
  unsigned int u = __float_as_uint(f);
  unsigned int r = (u + 0x7fffu + ((u >> 16) & 1u)) >> 16;
  return (unsigned short)r;
}
__device__ __forceinline__ float bf2f(unsigned short s) {
  return __uint_as_float((unsigned int)s << 16);
}

// ---- gemm block body: 32 rows x 128 cols, 4x4 register tile, bf16 W in LDS ----
__device__ __forceinline__ void gemm_block(
    const float* __restrict__ x, const unsigned short* __restrict__ Wl,
    unsigned short* __restrict__ xw, int bid, int tid) {
  const int c0 = (tid & 31) * 4;
  const int r0 = bid * 32 + (tid >> 5) * 4;
  if (r0 >= N_NODES) return;  // fine inside a device function

  float4 acc0 = {0, 0, 0, 0}, acc1 = acc0, acc2 = acc0, acc3 = acc0;
  const float* x0 = x + (size_t)r0 * D;

#define GEMM_STEP(J, HC)                                              \
  {                                                                   \
    ushort4 wu = *(const ushort4*)&Wl[(k4 + J) * D + c0];             \
    float wx = bf2f(wu.x), wy = bf2f(wu.y);                           \
    float wz = bf2f(wu.z), ww = bf2f(wu.w);                           \
    acc0.x = fmaf(hv0.HC, wx, acc0.x);                                \
    acc0.y = fmaf(hv0.HC, wy, acc0.y);                                \
    acc0.z = fmaf(hv0.HC, wz, acc0.z);                                \
    acc0.w = fmaf(hv0.HC, ww, acc0.w);                                \
    acc1.x = fmaf(hv1.HC, wx, acc1.x);                                \
    acc1.y = fmaf(hv1.HC, wy, acc1.y);                                \
    acc1.z = fmaf(hv1.HC, wz, acc1.z);                                \
    acc1.w = fmaf(hv1.HC, ww, acc1.w);                                \
    acc2.x = fmaf(hv2.HC, wx, acc2.x);                                \
    acc2.y = fmaf(hv2.HC, wy, acc2.y);                                \
    acc2.z = fmaf(hv2.HC, wz, acc2.z);                                \
    acc2.w = fmaf(hv2.HC, ww, acc2.w);                                \
    acc3.x = fmaf(hv3.HC, wx, acc3.x);                                \
    acc3.y = fmaf(hv3.HC, wy, acc3.y);                                \
    acc3.z = fmaf(hv3.HC, wz, acc3.z);                                \
    acc3.w = fmaf(hv3.HC, ww, acc3.w);                                \
  }

  for (int k4 = 0; k4 < D; k4 += 4) {
    float4 hv0 = *(const float4*)(x0 + 0 * D + k4);
    float4 hv1 = *(const float4*)(x0 + 1 * D + k4);
    float4 hv2 = *(const float4*)(x0 + 2 * D + k4);
    float4 hv3 = *(const float4*)(x0 + 3 * D + k4);
    GEMM_STEP(0, x)
    GEMM_STEP(1, y)
    GEMM_STEP(2, z)
    GEMM_STEP(3, w)
  }
#undef GEMM_STEP

  ushort4 sv;
#define STORE_ROW(R, ACC)                                              \
  sv.x = f2bf(ACC.x); sv.y = f2bf(ACC.y);                              \
  sv.z = f2bf(ACC.z); sv.w = f2bf(ACC.w);                              \
  *(ushort4*)(xw + (size_t)(r0 + R) * D + c0) = sv;
  STORE_ROW(0, acc0)
  STORE_ROW(1, acc1)
  STORE_ROW(2, acc2)
  STORE_ROW(3, acc3)
#undef STORE_ROW
}

// ---- gather body: one wave per node, lane l owns features 2l, 2l+1 ----
__device__ __forceinline__ void gather_node(
    const unsigned int* __restrict__ xw32, const int* __restrict__ counts,
    const unsigned short* __restrict__ srcs_pad, const float* __restrict__ b,
    float* __restrict__ out, int node, int lane) {
  int c = 0;
  if (lane < SHARDS) c = counts[lane * CSTRIDE + node];
  const unsigned short* npad = srcs_pad + (size_t)node * (SHARDS * BCAP);
  float alo = 0.f, ahi = 0.f;
#pragma unroll
  for (int s = 0; s < SHARDS; ++s) {
    int len = __shfl(c, s, 64);
    if (len > BCAP) len = BCAP;
    int id = npad[s * BCAP + (lane & 31)];  // lane j (and j+32) holds slot j
    for (int j = 0; j < len; ++j) {
      int sid = __shfl(id, j, 64);
      unsigned int u = xw32[sid * 64 + lane];  // coalesced 256B row per wave
      alo += __uint_as_float(u << 16);
      ahi += __uint_as_float(u & 0xffff0000u);
    }
  }
  const float2 bv = *(const float2*)(b + lane * 2);
  float2 o;
  o.x = fmaxf(alo + bv.x, 0.f);
  o.y = fmaxf(ahi + bv.y, 0.f);
  *(float2*)(out + (size_t)node * D + lane * 2) = o;
}

// ================= cooperative mega-kernel =================
__global__ __launch_bounds__(256, 4) void gcn_mega_kernel(
    const float* __restrict__ x, const float* __restrict__ W,
    const int* __restrict__ src, const int* __restrict__ dst,
    const float* __restrict__ b, float* __restrict__ out,
    unsigned short* __restrict__ xw, int* __restrict__ counts,
    unsigned short* __restrict__ srcs_pad) {
  cg::grid_group grid = cg::this_grid();
  __shared__ unsigned short Wl[D * D];  // 32 KB bf16 W

  // ---- phase 0: zero counts; gemm blocks stage W into LDS ----
  {
    int i = blockIdx.x * 256 + threadIdx.x;
    if (i < SHARDS * CSTRIDE) counts[i] = 0;
    if (blockIdx.x < GEMM_BLOCKS)
      for (int k = threadIdx.x; k < D * D; k += 256) Wl[k] = f2bf(W[k]);
  }
  grid.sync();

  // ---- phase 1: gemm (blocks < 313) || histfill (blocks 313..1023) ----
  if (blockIdx.x < GEMM_BLOCKS) {
    gemm_block(x, Wl, xw, blockIdx.x, threadIdx.x);
  } else {
    const int tbase = (blockIdx.x - GEMM_BLOCKS) * 256 + threadIdx.x;
    const int tstride = (NBLK - GEMM_BLOCKS) * 256;  // 182016
    const int sh = blockIdx.x & (SHARDS - 1);        // XCD-local bucket lines
    for (int e = tbase; e < N_EDGES; e += tstride) {
      int d = dst[e];
      int s = src[e];
      int r = atomicAdd(&counts[sh * CSTRIDE + d], 1);
      if (r < BCAP)  // Poisson(8)/bin: overflow prob ~1e-11
        srcs_pad[((size_t)d * SHARDS + sh) * BCAP + r] = (unsigned short)s;
    }
  }
  grid.sync();

  // ---- phase 2: gather, grid-stride over 2500 groups of 4 nodes ----
  {
    const unsigned int* xw32 = (const unsigned int*)xw;
    const int lane = threadIdx.x & 63;
    const int sub = threadIdx.x >> 6;
    for (int g = blockIdx.x; g < N_NODES / 4; g += NBLK) {
      gather_node(xw32, counts, srcs_pad, b, out, g * 4 + sub, lane);
    }
  }
}

// ================= fallback (non-cooperative) path =================
__global__ __launch_bounds__(256) void gcn_gemm_histfill_kernel(
    const float* __restrict__ x, const float* __restrict__ W,
    unsigned short* __restrict__ xw,
    const int* __restrict__ src, const int* __restrict__ dst,
    int* __restrict__ counts, unsigned short* __restrict__ srcs_pad) {
  __shared__ unsigned short Wl[D * D];
  if (blockIdx.x >= GEMM_BLOCKS) {
    int e = (blockIdx.x - GEMM_BLOCKS) * 256 + threadIdx.x;
    if (e < N_EDGES) {
      int d = dst[e];
      int s = src[e];
      int sh = blockIdx.x & (SHARDS - 1);
      int r = atomicAdd(&counts[sh * CSTRIDE + d], 1);
      if (r < BCAP)
        srcs_pad[((size_t)d * SHARDS + sh) * BCAP + r] = (unsigned short)s;
    }
    return;
  }
  for (int i = threadIdx.x; i < D * D; i += 256) Wl[i] = f2bf(W[i]);
  __syncthreads();
  gemm_block(x, Wl, xw, blockIdx.x, threadIdx.x);
}

__global__ __launch_bounds__(256) void gcn_gather_kernel(
    const unsigned short* __restrict__ xw, const int* __restrict__ counts,
    const unsigned short* __restrict__ srcs_pad,
    const float* __restrict__ b, float* __restrict__ out) {
  const int node = blockIdx.x * 4 + (threadIdx.x >> 6);
  const int lane = threadIdx.x & 63;
  gather_node((const unsigned int*)xw, counts, srcs_pad, b, out, node, lane);
}

extern "C" void kernel_launch(void* const* d_in, const int* in_sizes, int n_in,
                              void* d_out, int out_size, void* d_ws, size_t ws_size,
                              hipStream_t stream) {
  const float* x   = (const float*)d_in[0];
  const int*   src = (const int*)d_in[1];
  const int*   dst = (const int*)d_in[2];
  const float* W   = (const float*)d_in[3];
  const float* b   = (const float*)d_in[4];
  float* out = (float*)d_out;

  // Workspace layout (~8 MB)
  unsigned short* xw       = (unsigned short*)d_ws;              // 1,280,000 u16 (2.56 MB)
  int*            counts   = (int*)(xw + (size_t)N_NODES * D);   // 8*10016 ints (320 KB)
  unsigned short* srcs_pad = (unsigned short*)(counts + SHARDS * CSTRIDE);
                                                                 // 10000*8*32 u16 (5.12 MB)

  void* args[] = {(void*)&x, (void*)&W, (void*)&src, (void*)&dst, (void*)&b,
                  (void*)&out, (void*)&xw, (void*)&counts, (void*)&srcs_pad};
  hipError_t err = hipLaunchCooperativeKernel(
      (const void*)gcn_mega_kernel, dim3(NBLK), dim3(256), args, 0, stream);

  if (err != hipSuccess) {
    // Fallback: 3-dispatch non-cooperative pipeline (round-7 structure)
    hipMemsetAsync(counts, 0, SHARDS * CSTRIDE * sizeof(int), stream);
    gcn_gemm_histfill_kernel<<<GEMM_BLOCKS + FILL_BLOCKS, 256, 0, stream>>>(
        x, W, xw, src, dst, counts, srcs_pad);
    gcn_gather_kernel<<<N_NODES / 4, 256, 0, stream>>>(xw, counts, srcs_pad, b, out);
  }
}

// Round 10
// 143.954 us; speedup vs baseline: 2.6088x; 2.6088x over previous
//
#include <hip/hip_runtime.h>

#define N_NODES 10000
#define D 128
#define N_EDGES 640000
#define SHARDS 16
#define CSTRIDE 10016     // per-shard counter stride (ints); shards on distinct lines
#define BCAP 32           // slots per (node,shard) bucket; 32 * 2B = one 64B line
#define GEMM_BLOCKS 313   // ceil(10000/32)

// bf16 round-to-nearest-even
__device__ __forceinline__ unsigned short f2bf(float f) {
  unsigned int u = __float_as_uint(f);
  unsigned int r = (u + 0x7fffu + ((u >> 16) & 1u)) >> 16;
  return (unsigned short)r;
}
__device__ __forceinline__ float bf2f(unsigned short s) {
  return __uint_as_float((unsigned int)s << 16);
}

// ---- Pass A: xw = x @ W (bf16 out). 32 rows x 128 cols/block, 4x4 tile. ----
// W staged in LDS as bf16: 32 KB -> 5 blocks/CU.
__global__ __launch_bounds__(256) void gcn_gemm_kernel(
    const float* __restrict__ x, const float* __restrict__ W,
    unsigned short* __restrict__ xw) {
  __shared__ unsigned short Wl[D * D];  // 32 KB
  for (int i = threadIdx.x; i < D * D; i += 256) Wl[i] = f2bf(W[i]);
  __syncthreads();

  const int c0 = (threadIdx.x & 31) * 4;
  const int r0 = blockIdx.x * 32 + (threadIdx.x >> 5) * 4;
  if (r0 >= N_NODES) return;

  float4 acc0 = {0, 0, 0, 0}, acc1 = acc0, acc2 = acc0, acc3 = acc0;
  const float* x0 = x + (size_t)r0 * D;

#define GEMM_STEP(J, HC)                                              \
  {                                                                   \
    ushort4 wu = *(const ushort4*)&Wl[(k4 + J) * D + c0];             \
    float wx = bf2f(wu.x), wy = bf2f(wu.y);                           \
    float wz = bf2f(wu.z), ww = bf2f(wu.w);                           \
    acc0.x = fmaf(hv0.HC, wx, acc0.x);                                \
    acc0.y = fmaf(hv0.HC, wy, acc0.y);                                \
    acc0.z = fmaf(hv0.HC, wz, acc0.z);                                \
    acc0.w = fmaf(hv0.HC, ww, acc0.w);                                \
    acc1.x = fmaf(hv1.HC, wx, acc1.x);                                \
    acc1.y = fmaf(hv1.HC, wy, acc1.y);                                \
    acc1.z = fmaf(hv1.HC, wz, acc1.z);                                \
    acc1.w = fmaf(hv1.HC, ww, acc1.w);                                \
    acc2.x = fmaf(hv2.HC, wx, acc2.x);                                \
    acc2.y = fmaf(hv2.HC, wy, acc2.y);                                \
    acc2.z = fmaf(hv2.HC, wz, acc2.z);                                \
    acc2.w = fmaf(hv2.HC, ww, acc2.w);                                \
    acc3.x = fmaf(hv3.HC, wx, acc3.x);                                \
    acc3.y = fmaf(hv3.HC, wy, acc3.y);                                \
    acc3.z = fmaf(hv3.HC, wz, acc3.z);                                \
    acc3.w = fmaf(hv3.HC, ww, acc3.w);                                \
  }

  for (int k4 = 0; k4 < D; k4 += 4) {
    float4 hv0 = *(const float4*)(x0 + 0 * D + k4);
    float4 hv1 = *(const float4*)(x0 + 1 * D + k4);
    float4 hv2 = *(const float4*)(x0 + 2 * D + k4);
    float4 hv3 = *(const float4*)(x0 + 3 * D + k4);
    GEMM_STEP(0, x)
    GEMM_STEP(1, y)
    GEMM_STEP(2, z)
    GEMM_STEP(3, w)
  }
#undef GEMM_STEP

  ushort4 sv;
#define STORE_ROW(R, ACC)                                              \
  sv.x = f2bf(ACC.x); sv.y = f2bf(ACC.y);                              \
  sv.z = f2bf(ACC.z); sv.w = f2bf(ACC.w);                              \
  *(ushort4*)(xw + (size_t)(r0 + R) * D + c0) = sv;
  STORE_ROW(0, acc0)
  STORE_ROW(1, acc1)
  STORE_ROW(2, acc2)
  STORE_ROW(3, acc3)
#undef STORE_ROW
}

// ---- Pass B: histogram + bucket fill. 4 edges/thread (int4 loads, 4 ----
// independent atomic chains). shard = blockIdx & 15: with 8 XCDs, shard s is
// only ever touched by XCD (s&7) -> counter/bucket lines stay XCD-local.
__global__ __launch_bounds__(256) void gcn_histfill_kernel(
    const int* __restrict__ src, const int* __restrict__ dst,
    int* __restrict__ counts, unsigned short* __restrict__ srcs_pad) {
  const int e4 = (blockIdx.x * 256 + threadIdx.x) * 4;  // 625 blocks exact
  const int sh = blockIdx.x & (SHARDS - 1);
  const int4 d4 = *(const int4*)(dst + e4);
  const int4 s4 = *(const int4*)(src + e4);
  int* csh = counts + sh * CSTRIDE;

  int r0 = atomicAdd(&csh[d4.x], 1);
  int r1 = atomicAdd(&csh[d4.y], 1);
  int r2 = atomicAdd(&csh[d4.z], 1);
  int r3 = atomicAdd(&csh[d4.w], 1);
  // Poisson(4)/bin: P(>32) ~ 0; guard anyway
  if (r0 < BCAP) srcs_pad[((size_t)d4.x * SHARDS + sh) * BCAP + r0] = (unsigned short)s4.x;
  if (r1 < BCAP) srcs_pad[((size_t)d4.y * SHARDS + sh) * BCAP + r1] = (unsigned short)s4.y;
  if (r2 < BCAP) srcs_pad[((size_t)d4.z * SHARDS + sh) * BCAP + r2] = (unsigned short)s4.z;
  if (r3 < BCAP) srcs_pad[((size_t)d4.w * SHARDS + sh) * BCAP + r3] = (unsigned short)s4.w;
}

// ---- Pass C: gather-sum, one wave per node (wave-uniform bounds, zero ----
// divergence). Lane l owns features 2l,2l+1 (one packed-bf16 uint per row).
__global__ __launch_bounds__(256) void gcn_gather_kernel(
    const unsigned short* __restrict__ xw, const int* __restrict__ counts,
    const unsigned short* __restrict__ srcs_pad,
    const float* __restrict__ b, float* __restrict__ out) {
  const int node = blockIdx.x * 4 + (threadIdx.x >> 6);  // 2500 blocks exact
  const int lane = threadIdx.x & 63;

  int c = 0;
  if (lane < SHARDS) c = counts[lane * CSTRIDE + node];  // lane s -> count[s]

  const unsigned short* npad = srcs_pad + (size_t)node * (SHARDS * BCAP);
  const unsigned int* xw32 = (const unsigned int*)xw;  // 2 bf16 per uint
  float alo = 0.f, ahi = 0.f;

#pragma unroll
  for (int s = 0; s < SHARDS; ++s) {
    int len = __shfl(c, s, 64);
    if (len > BCAP) len = BCAP;
    int id = npad[s * BCAP + (lane & 31)];  // lane j (and j+32) holds slot j
    int j = 0;
    for (; j + 2 <= len; j += 2) {  // 2 loads in flight
      int sid0 = __shfl(id, j, 64);
      int sid1 = __shfl(id, j + 1, 64);
      unsigned int u0 = xw32[sid0 * 64 + lane];  // coalesced 256B row/wave
      unsigned int u1 = xw32[sid1 * 64 + lane];
      alo += __uint_as_float(u0 << 16);
      ahi += __uint_as_float(u0 & 0xffff0000u);
      alo += __uint_as_float(u1 << 16);
      ahi += __uint_as_float(u1 & 0xffff0000u);
    }
    if (j < len) {
      int sid = __shfl(id, j, 64);
      unsigned int u = xw32[sid * 64 + lane];
      alo += __uint_as_float(u << 16);
      ahi += __uint_as_float(u & 0xffff0000u);
    }
  }

  const float2 bv = *(const float2*)(b + lane * 2);
  float2 o;
  o.x = fmaxf(alo + bv.x, 0.f);
  o.y = fmaxf(ahi + bv.y, 0.f);
  *(float2*)(out + (size_t)node * D + lane * 2) = o;
}

extern "C" void kernel_launch(void* const* d_in, const int* in_sizes, int n_in,
                              void* d_out, int out_size, void* d_ws, size_t ws_size,
                              hipStream_t stream) {
  const float* x   = (const float*)d_in[0];
  const int*   src = (const int*)d_in[1];
  const int*   dst = (const int*)d_in[2];
  const float* W   = (const float*)d_in[3];
  const float* b   = (const float*)d_in[4];
  float* out = (float*)d_out;

  // Workspace layout (~13.5 MB)
  unsigned short* xw       = (unsigned short*)d_ws;              // 1,280,000 u16 (2.56 MB)
  int*            counts   = (int*)(xw + (size_t)N_NODES * D);   // 16*10016 ints (641 KB)
  unsigned short* srcs_pad = (unsigned short*)(counts + SHARDS * CSTRIDE);
                                                                 // 10000*16*32 u16 (10.24 MB)

  hipMemsetAsync(counts, 0, SHARDS * CSTRIDE * sizeof(int), stream);
  gcn_gemm_kernel<<<GEMM_BLOCKS, 256, 0, stream>>>(x, W, xw);
  gcn_histfill_kernel<<<N_EDGES / (256 * 4), 256, 0, stream>>>(src, dst, counts, srcs_pad);
  gcn_gather_kernel<<<N_NODES / 4, 256, 0, stream>>>(xw, counts, srcs_pad, b, out);
}

// Round 11
// 128.866 us; speedup vs baseline: 2.9142x; 1.1171x over previous
//
#include <hip/hip_runtime.h>

#define N_NODES 10000
#define D 128
#define N_EDGES 640000
#define SHARDS 8
#define CSTRIDE 10016     // per-shard counter stride (ints); shards on distinct lines
#define BCAP 32           // slots per (node,shard) bucket; 32 * 2B = one 64B line
#define GEMM_BLOCKS 313   // ceil(10000/32)
#define FILL_BLOCKS 625   // 640000 / (256*4)

// bf16 round-to-nearest-even
__device__ __forceinline__ unsigned short f2bf(float f) {
  unsigned int u = __float_as_uint(f);
  unsigned int r = (u + 0x7fffu + ((u >> 16) & 1u)) >> 16;
  return (unsigned short)r;
}
__device__ __forceinline__ float bf2f(unsigned short s) {
  return __uint_as_float((unsigned int)s << 16);
}

// ---- Launch 2 (fused): blocks [0,625) histfill (4 edges/thread, the longer
// pole, so it starts first); blocks [625,938) compute xw = x@W (bf16 out).
// 938 blocks at 32KB LDS = single co-residency wave (5 blocks/CU cap).
__global__ __launch_bounds__(256) void gcn_fused_kernel(
    const float* __restrict__ x, const float* __restrict__ W,
    unsigned short* __restrict__ xw,
    const int* __restrict__ src, const int* __restrict__ dst,
    int* __restrict__ counts, unsigned short* __restrict__ srcs_pad) {
  __shared__ unsigned short Wl[D * D];  // 32 KB bf16 W (gemm blocks only)

  if (blockIdx.x < FILL_BLOCKS) {
    // ---- histfill: 4 edges/thread, int4 loads, 4 independent atomic chains.
    // shard = blockIdx & 7 ~ XCD id: counter+bucket lines stay XCD-local.
    const int e4 = (blockIdx.x * 256 + threadIdx.x) * 4;
    const int sh = blockIdx.x & (SHARDS - 1);
    const int4 d4 = *(const int4*)(dst + e4);
    const int4 s4 = *(const int4*)(src + e4);
    int* csh = counts + sh * CSTRIDE;

    int r0 = atomicAdd(&csh[d4.x], 1);
    int r1 = atomicAdd(&csh[d4.y], 1);
    int r2 = atomicAdd(&csh[d4.z], 1);
    int r3 = atomicAdd(&csh[d4.w], 1);
    // Poisson(8)/bin: P(>32) ~ 1e-11; guard anyway
    if (r0 < BCAP) srcs_pad[((size_t)d4.x * SHARDS + sh) * BCAP + r0] = (unsigned short)s4.x;
    if (r1 < BCAP) srcs_pad[((size_t)d4.y * SHARDS + sh) * BCAP + r1] = (unsigned short)s4.y;
    if (r2 < BCAP) srcs_pad[((size_t)d4.z * SHARDS + sh) * BCAP + r2] = (unsigned short)s4.z;
    if (r3 < BCAP) srcs_pad[((size_t)d4.w * SHARDS + sh) * BCAP + r3] = (unsigned short)s4.w;
    return;
  }

  // ---- gemm: 32 rows x 128 cols per block, 4x4 register tile ----
  for (int i = threadIdx.x; i < D * D; i += 256) Wl[i] = f2bf(W[i]);
  __syncthreads();

  const int bid = blockIdx.x - FILL_BLOCKS;
  const int c0 = (threadIdx.x & 31) * 4;
  const int r0 = bid * 32 + (threadIdx.x >> 5) * 4;
  if (r0 >= N_NODES) return;

  float4 acc0 = {0, 0, 0, 0}, acc1 = acc0, acc2 = acc0, acc3 = acc0;
  const float* x0 = x + (size_t)r0 * D;

#define GEMM_STEP(J, HC)                                              \
  {                                                                   \
    ushort4 wu = *(const ushort4*)&Wl[(k4 + J) * D + c0];             \
    float wx = bf2f(wu.x), wy = bf2f(wu.y);                           \
    float wz = bf2f(wu.z), ww = bf2f(wu.w);                           \
    acc0.x = fmaf(hv0.HC, wx, acc0.x);                                \
    acc0.y = fmaf(hv0.HC, wy, acc0.y);                                \
    acc0.z = fmaf(hv0.HC, wz, acc0.z);                                \
    acc0.w = fmaf(hv0.HC, ww, acc0.w);                                \
    acc1.x = fmaf(hv1.HC, wx, acc1.x);                                \
    acc1.y = fmaf(hv1.HC, wy, acc1.y);                                \
    acc1.z = fmaf(hv1.HC, wz, acc1.z);                                \
    acc1.w = fmaf(hv1.HC, ww, acc1.w);                                \
    acc2.x = fmaf(hv2.HC, wx, acc2.x);                                \
    acc2.y = fmaf(hv2.HC, wy, acc2.y);                                \
    acc2.z = fmaf(hv2.HC, wz, acc2.z);                                \
    acc2.w = fmaf(hv2.HC, ww, acc2.w);                                \
    acc3.x = fmaf(hv3.HC, wx, acc3.x);                                \
    acc3.y = fmaf(hv3.HC, wy, acc3.y);                                \
    acc3.z = fmaf(hv3.HC, wz, acc3.z);                                \
    acc3.w = fmaf(hv3.HC, ww, acc3.w);                                \
  }

  for (int k4 = 0; k4 < D; k4 += 4) {
    float4 hv0 = *(const float4*)(x0 + 0 * D + k4);
    float4 hv1 = *(const float4*)(x0 + 1 * D + k4);
    float4 hv2 = *(const float4*)(x0 + 2 * D + k4);
    float4 hv3 = *(const float4*)(x0 + 3 * D + k4);
    GEMM_STEP(0, x)
    GEMM_STEP(1, y)
    GEMM_STEP(2, z)
    GEMM_STEP(3, w)
  }
#undef GEMM_STEP

  ushort4 sv;
#define STORE_ROW(R, ACC)                                              \
  sv.x = f2bf(ACC.x); sv.y = f2bf(ACC.y);                              \
  sv.z = f2bf(ACC.z); sv.w = f2bf(ACC.w);                              \
  *(ushort4*)(xw + (size_t)(r0 + R) * D + c0) = sv;
  STORE_ROW(0, acc0)
  STORE_ROW(1, acc1)
  STORE_ROW(2, acc2)
  STORE_ROW(3, acc3)
#undef STORE_ROW
}

// ---- Launch 3: gather-sum, one wave per node (wave-uniform bounds, zero
// divergence). Lane l owns features 2l,2l+1 (one packed-bf16 uint per row);
// edge ids distributed in-register via shfl; 2-deep row-load unroll for MLP.
__global__ __launch_bounds__(256) void gcn_gather_kernel(
    const unsigned short* __restrict__ xw, const int* __restrict__ counts,
    const unsigned short* __restrict__ srcs_pad,
    const float* __restrict__ b, float* __restrict__ out) {
  const int node = blockIdx.x * 4 + (threadIdx.x >> 6);  // 2500 blocks exact
  const int lane = threadIdx.x & 63;

  int c = 0;
  if (lane < SHARDS) c = counts[lane * CSTRIDE + node];  // lane s -> count[s]

  const unsigned short* npad = srcs_pad + (size_t)node * (SHARDS * BCAP);
  const unsigned int* xw32 = (const unsigned int*)xw;  // 2 bf16 per uint
  float alo = 0.f, ahi = 0.f;

#pragma unroll
  for (int s = 0; s < SHARDS; ++s) {
    int len = __shfl(c, s, 64);
    if (len > BCAP) len = BCAP;
    int id = npad[s * BCAP + (lane & 31)];  // lane j (and j+32) holds slot j
    int j = 0;
    for (; j + 2 <= len; j += 2) {  // 2 loads in flight
      int sid0 = __shfl(id, j, 64);
      int sid1 = __shfl(id, j + 1, 64);
      unsigned int u0 = xw32[sid0 * 64 + lane];  // coalesced 256B row/wave
      unsigned int u1 = xw32[sid1 * 64 + lane];
      alo += __uint_as_float(u0 << 16);
      ahi += __uint_as_float(u0 & 0xffff0000u);
      alo += __uint_as_float(u1 << 16);
      ahi += __uint_as_float(u1 & 0xffff0000u);
    }
    if (j < len) {
      int sid = __shfl(id, j, 64);
      unsigned int u = xw32[sid * 64 + lane];
      alo += __uint_as_float(u << 16);
      ahi += __uint_as_float(u & 0xffff0000u);
    }
  }

  const float2 bv = *(const float2*)(b + lane * 2);
  float2 o;
  o.x = fmaxf(alo + bv.x, 0.f);
  o.y = fmaxf(ahi + bv.y, 0.f);
  *(float2*)(out + (size_t)node * D + lane * 2) = o;
}

extern "C" void kernel_launch(void* const* d_in, const int* in_sizes, int n_in,
                              void* d_out, int out_size, void* d_ws, size_t ws_size,
                              hipStream_t stream) {
  const float* x   = (const float*)d_in[0];
  const int*   src = (const int*)d_in[1];
  const int*   dst = (const int*)d_in[2];
  const float* W   = (const float*)d_in[3];
  const float* b   = (const float*)d_in[4];
  float* out = (float*)d_out;

  // Workspace layout (~8 MB)
  unsigned short* xw       = (unsigned short*)d_ws;              // 1,280,000 u16 (2.56 MB)
  int*            counts   = (int*)(xw + (size_t)N_NODES * D);   // 8*10016 ints (320 KB)
  unsigned short* srcs_pad = (unsigned short*)(counts + SHARDS * CSTRIDE);
                                                                 // 10000*8*32 u16 (5.12 MB)

  hipMemsetAsync(counts, 0, SHARDS * CSTRIDE * sizeof(int), stream);
  gcn_fused_kernel<<<FILL_BLOCKS + GEMM_BLOCKS, 256, 0, stream>>>(
      x, W, xw, src, dst, counts, srcs_pad);
  gcn_gather_kernel<<<N_NODES / 4, 256, 0, stream>>>(xw, counts, srcs_pad, b, out);
}

// Round 12
// 125.424 us; speedup vs baseline: 2.9942x; 1.0274x over previous
//
#include <hip/hip_runtime.h>

#define N_NODES 10000
#define D 128
#define N_EDGES 640000
#define SHARDS 8
#define CPAD 16           // ints per counter slot: one full 64B line per counter
#define BCAP 32           // slots per (node,shard) bucket; 32 * 2B = one 64B line
#define GEMM_BLOCKS 313   // ceil(10000/32)
#define FILL_BLOCKS 625   // 640000 / (256*4)

// bf16 round-to-nearest-even
__device__ __forceinline__ unsigned short f2bf(float f) {
  unsigned int u = __float_as_uint(f);
  unsigned int r = (u + 0x7fffu + ((u >> 16) & 1u)) >> 16;
  return (unsigned short)r;
}
__device__ __forceinline__ float bf2f(unsigned short s) {
  return __uint_as_float((unsigned int)s << 16);
}

// counter index: every (node,shard) counter on its own 64B line so TCC
// atomic ALUs never serialize different counters on one line.
__device__ __forceinline__ int cidx(int d, int sh) {
  return ((d << 3) | sh) << 4;  // (d*8+sh)*16 ints
}

// ---- Launch 2 (fused): blocks [0,625) histfill (4 edges/thread, longer
// pole, starts first); blocks [625,938) compute xw = x@W (bf16 out).
// 938 blocks at 32KB LDS = single co-residency wave (5 blocks/CU cap).
__global__ __launch_bounds__(256) void gcn_fused_kernel(
    const float* __restrict__ x, const float* __restrict__ W,
    unsigned short* __restrict__ xw,
    const int* __restrict__ src, const int* __restrict__ dst,
    int* __restrict__ counts, unsigned short* __restrict__ srcs_pad) {
  __shared__ unsigned short Wl[D * D];  // 32 KB bf16 W (gemm blocks only)

  if (blockIdx.x < FILL_BLOCKS) {
    // ---- histfill: 4 edges/thread, int4 loads, 4 independent atomic chains.
    // shard = blockIdx & 7 ~ XCD id: counter+bucket lines stay XCD-local.
    const int e4 = (blockIdx.x * 256 + threadIdx.x) * 4;
    const int sh = blockIdx.x & (SHARDS - 1);
    const int4 d4 = *(const int4*)(dst + e4);
    const int4 s4 = *(const int4*)(src + e4);

    int r0 = atomicAdd(&counts[cidx(d4.x, sh)], 1);
    int r1 = atomicAdd(&counts[cidx(d4.y, sh)], 1);
    int r2 = atomicAdd(&counts[cidx(d4.z, sh)], 1);
    int r3 = atomicAdd(&counts[cidx(d4.w, sh)], 1);
    // Poisson(8)/bin: P(>32) ~ 1e-11; guard anyway
    if (r0 < BCAP) srcs_pad[((size_t)d4.x * SHARDS + sh) * BCAP + r0] = (unsigned short)s4.x;
    if (r1 < BCAP) srcs_pad[((size_t)d4.y * SHARDS + sh) * BCAP + r1] = (unsigned short)s4.y;
    if (r2 < BCAP) srcs_pad[((size_t)d4.z * SHARDS + sh) * BCAP + r2] = (unsigned short)s4.z;
    if (r3 < BCAP) srcs_pad[((size_t)d4.w * SHARDS + sh) * BCAP + r3] = (unsigned short)s4.w;
    return;
  }

  // ---- gemm: 32 rows x 128 cols per block, 4x4 register tile ----
  for (int i = threadIdx.x; i < D * D; i += 256) Wl[i] = f2bf(W[i]);
  __syncthreads();

  const int bid = blockIdx.x - FILL_BLOCKS;
  const int c0 = (threadIdx.x & 31) * 4;
  const int r0 = bid * 32 + (threadIdx.x >> 5) * 4;
  if (r0 >= N_NODES) return;

  float4 acc0 = {0, 0, 0, 0}, acc1 = acc0, acc2 = acc0, acc3 = acc0;
  const float* x0 = x + (size_t)r0 * D;

#define GEMM_STEP(J, HC)                                              \
  {                                                                   \
    ushort4 wu = *(const ushort4*)&Wl[(k4 + J) * D + c0];             \
    float wx = bf2f(wu.x), wy = bf2f(wu.y);                           \
    float wz = bf2f(wu.z), ww = bf2f(wu.w);                           \
    acc0.x = fmaf(hv0.HC, wx, acc0.x);                                \
    acc0.y = fmaf(hv0.HC, wy, acc0.y);                                \
    acc0.z = fmaf(hv0.HC, wz, acc0.z);                                \
    acc0.w = fmaf(hv0.HC, ww, acc0.w);                                \
    acc1.x = fmaf(hv1.HC, wx, acc1.x);                                \
    acc1.y = fmaf(hv1.HC, wy, acc1.y);                                \
    acc1.z = fmaf(hv1.HC, wz, acc1.z);                                \
    acc1.w = fmaf(hv1.HC, ww, acc1.w);                                \
    acc2.x = fmaf(hv2.HC, wx, acc2.x);                                \
    acc2.y = fmaf(hv2.HC, wy, acc2.y);                                \
    acc2.z = fmaf(hv2.HC, wz, acc2.z);                                \
    acc2.w = fmaf(hv2.HC, ww, acc2.w);                                \
    acc3.x = fmaf(hv3.HC, wx, acc3.x);                                \
    acc3.y = fmaf(hv3.HC, wy, acc3.y);                                \
    acc3.z = fmaf(hv3.HC, wz, acc3.z);                                \
    acc3.w = fmaf(hv3.HC, ww, acc3.w);                                \
  }

  for (int k4 = 0; k4 < D; k4 += 4) {
    float4 hv0 = *(const float4*)(x0 + 0 * D + k4);
    float4 hv1 = *(const float4*)(x0 + 1 * D + k4);
    float4 hv2 = *(const float4*)(x0 + 2 * D + k4);
    float4 hv3 = *(const float4*)(x0 + 3 * D + k4);
    GEMM_STEP(0, x)
    GEMM_STEP(1, y)
    GEMM_STEP(2, z)
    GEMM_STEP(3, w)
  }
#undef GEMM_STEP

  ushort4 sv;
#define STORE_ROW(R, ACC)                                              \
  sv.x = f2bf(ACC.x); sv.y = f2bf(ACC.y);                              \
  sv.z = f2bf(ACC.z); sv.w = f2bf(ACC.w);                              \
  *(ushort4*)(xw + (size_t)(r0 + R) * D + c0) = sv;
  STORE_ROW(0, acc0)
  STORE_ROW(1, acc1)
  STORE_ROW(2, acc2)
  STORE_ROW(3, acc3)
#undef STORE_ROW
}

// ---- Launch 3: gather-sum, one wave per node (wave-uniform bounds, zero
// divergence). Lane l owns features 2l,2l+1 (one packed-bf16 uint per row);
// edge ids distributed in-register via shfl; 4-deep row-load unroll.
__global__ __launch_bounds__(256) void gcn_gather_kernel(
    const unsigned short* __restrict__ xw, const int* __restrict__ counts,
    const unsigned short* __restrict__ srcs_pad,
    const float* __restrict__ b, float* __restrict__ out) {
  const int node = blockIdx.x * 4 + (threadIdx.x >> 6);  // 2500 blocks exact
  const int lane = threadIdx.x & 63;

  int c = 0;
  if (lane < SHARDS) c = counts[cidx(node, lane)];  // lane s -> count[s]

  const unsigned short* npad = srcs_pad + (size_t)node * (SHARDS * BCAP);
  const unsigned int* xw32 = (const unsigned int*)xw;  // 2 bf16 per uint
  float alo = 0.f, ahi = 0.f;

#pragma unroll
  for (int s = 0; s < SHARDS; ++s) {
    int len = __shfl(c, s, 64);
    if (len > BCAP) len = BCAP;
    int id = npad[s * BCAP + (lane & 31)];  // lane j (and j+32) holds slot j
    int j = 0;
    for (; j + 4 <= len; j += 4) {  // 4 loads in flight
      int sid0 = __shfl(id, j + 0, 64);
      int sid1 = __shfl(id, j + 1, 64);
      int sid2 = __shfl(id, j + 2, 64);
      int sid3 = __shfl(id, j + 3, 64);
      unsigned int u0 = xw32[sid0 * 64 + lane];  // coalesced 256B row/wave
      unsigned int u1 = xw32[sid1 * 64 + lane];
      unsigned int u2 = xw32[sid2 * 64 + lane];
      unsigned int u3 = xw32[sid3 * 64 + lane];
      alo += __uint_as_float(u0 << 16);
      ahi += __uint_as_float(u0 & 0xffff0000u);
      alo += __uint_as_float(u1 << 16);
      ahi += __uint_as_float(u1 & 0xffff0000u);
      alo += __uint_as_float(u2 << 16);
      ahi += __uint_as_float(u2 & 0xffff0000u);
      alo += __uint_as_float(u3 << 16);
      ahi += __uint_as_float(u3 & 0xffff0000u);
    }
    if (j + 2 <= len) {
      int sid0 = __shfl(id, j + 0, 64);
      int sid1 = __shfl(id, j + 1, 64);
      unsigned int u0 = xw32[sid0 * 64 + lane];
      unsigned int u1 = xw32[sid1 * 64 + lane];
      alo += __uint_as_float(u0 << 16);
      ahi += __uint_as_float(u0 & 0xffff0000u);
      alo += __uint_as_float(u1 << 16);
      ahi += __uint_as_float(u1 & 0xffff0000u);
      j += 2;
    }
    if (j < len) {
      int sid = __shfl(id, j, 64);
      unsigned int u = xw32[sid * 64 + lane];
      alo += __uint_as_float(u << 16);
      ahi += __uint_as_float(u & 0xffff0000u);
    }
  }

  const float2 bv = *(const float2*)(b + lane * 2);
  float2 o;
  o.x = fmaxf(alo + bv.x, 0.f);
  o.y = fmaxf(ahi + bv.y, 0.f);
  *(float2*)(out + (size_t)node * D + lane * 2) = o;
}

extern "C" void kernel_launch(void* const* d_in, const int* in_sizes, int n_in,
                              void* d_out, int out_size, void* d_ws, size_t ws_size,
                              hipStream_t stream) {
  const float* x   = (const float*)d_in[0];
  const int*   src = (const int*)d_in[1];
  const int*   dst = (const int*)d_in[2];
  const float* W   = (const float*)d_in[3];
  const float* b   = (const float*)d_in[4];
  float* out = (float*)d_out;

  // Workspace layout (~12.8 MB)
  unsigned short* xw       = (unsigned short*)d_ws;              // 1,280,000 u16 (2.56 MB)
  int*            counts   = (int*)(xw + (size_t)N_NODES * D);   // 10000*8*16 ints (5.12 MB)
  unsigned short* srcs_pad = (unsigned short*)(counts + (size_t)N_NODES * SHARDS * CPAD);
                                                                 // 10000*8*32 u16 (5.12 MB)

  hipMemsetAsync(counts, 0, (size_t)N_NODES * SHARDS * CPAD * sizeof(int), stream);
  gcn_fused_kernel<<<FILL_BLOCKS + GEMM_BLOCKS, 256, 0, stream>>>(
      x, W, xw, src, dst, counts, srcs_pad);
  gcn_gather_kernel<<<N_NODES / 4, 256, 0, stream>>>(xw, counts, srcs_pad, b, out);
}